// Round 7
// baseline (274.467 us; speedup 1.0000x reference)
//
#include <hip/hip_runtime.h>
#include <stdint.h>

typedef float f32x4 __attribute__((ext_vector_type(4)));
typedef short bf16x8 __attribute__((ext_vector_type(8)));
typedef float fragc __attribute__((ext_vector_type(4)));
typedef uint32_t u32x4 __attribute__((ext_vector_type(4)));

__device__ __forceinline__ uint32_t pk2(float lo, float hi) {
  // (bf16(lo) | bf16(hi)<<16) via one v_perm_b32 (truncating)
  return __builtin_amdgcn_perm(__float_as_uint(hi), __float_as_uint(lo), 0x07060302u);
}

__device__ __forceinline__ void gload16(const void* g, void* l) {
  __builtin_amdgcn_global_load_lds((const __attribute__((address_space(1))) uint32_t*)g,
                                   (__attribute__((address_space(3))) uint32_t*)l, 16, 0, 0);
}

#define WS_B_OFF 67108864ull  // B'' at ws + 64 MiB

// ---------- Pass 1: [1024 s][512 r][64 h] f32 -> bf16 ws[kq 128][h 64][r 512][16B octet]
// NT loads: originals are touched once -> don't let them evict packed data from L3.
__global__ __launch_bounds__(512) void pack_kernel(const float* __restrict__ Ag,
                                                   const float* __restrict__ Bg,
                                                   uint8_t* __restrict__ ws) {
  __shared__ alignas(16) uint8_t lds[65536];

  const int bid  = blockIdx.x;
  const int rw   = bid & 7;
  const int kq   = (bid >> 3) & 127;
  const int side = bid >> 10;
  const int t    = threadIdx.x;

  const f32x4* S4 = (const f32x4*)(side ? Bg : Ag);
  uint8_t* dst = ws + (side ? WS_B_OFF : 0ull);

  // window = rows rw*64..+63 (1024 float4); thread owns rows {t>>4, t>>4+32}, h-quad t&15
  const int base = rw * 1024 + t;
  f32x4 r1[8], r2[8];
#pragma unroll
  for (int e = 0; e < 8; ++e) {
    r1[e] = __builtin_nontemporal_load(&S4[(size_t)(kq * 8 + e) * 8192 + base]);
    r2[e] = __builtin_nontemporal_load(&S4[(size_t)(kq * 8 + e) * 8192 + base + 512]);
  }

  const int hq = t & 15;
  const int ra = t >> 4;  // 0..31
#pragma unroll
  for (int e = 0; e < 4; ++e) {
    const int h = hq * 4 + e;
    u32x4 o1, o2;
    o1[0] = pk2(r1[0][e], r1[1][e]); o1[1] = pk2(r1[2][e], r1[3][e]);
    o1[2] = pk2(r1[4][e], r1[5][e]); o1[3] = pk2(r1[6][e], r1[7][e]);
    o2[0] = pk2(r2[0][e], r2[1][e]); o2[1] = pk2(r2[2][e], r2[3][e]);
    o2[2] = pk2(r2[4][e], r2[5][e]); o2[3] = pk2(r2[6][e], r2[7][e]);
    const int s1 = (ra + hq) & 63;
    const int s2 = (ra + 32 + hq) & 63;
    *(u32x4*)(lds + h * 1024 + s1 * 16) = o1;
    *(u32x4*)(lds + h * 1024 + s2 * 16) = o2;
  }
  __syncthreads();

  const int l = t & 63, w = t >> 6;
#pragma unroll
  for (int e2 = 0; e2 < 8; ++e2) {
    const int h  = e2 * 8 + w;
    const int sl = (l + (h >> 2)) & 63;
    const u32x4 v = *(const u32x4*)(lds + h * 1024 + sl * 16);
    *(u32x4*)(dst + ((size_t)(kq * 64 + h) * 512 + rw * 64 + l) * 16) = v;  // cached: feeds gemm
  }
}

// ---------- Pass 2: C[i,j,h] = (1/1024) sum_s A''[.,h,i]*B''[.,h,j]
// tile 128i x 128j x 4h, 512 thr (8 waves: hl = w&3, half = w>>2), BK=32, dbuf LDS 128KB.
// XCD map: x = (i-pair, j-pair, h-half) -> each A/B byte re-read only within its XCD (2x,
// kt-synced -> L2 serves), and all 4 hg-siblings of every C-line are co-XCD (write merge).
__global__ __launch_bounds__(512, 2) void gemm_kernel(const uint8_t* __restrict__ ws,
                                                      float* __restrict__ Og) {
  __shared__ alignas(16) uint8_t lds[131072];  // 2 x (A 32KB + B 32KB)

  const int bid = blockIdx.x;
  const int x   = bid & 7;
  const int r   = bid >> 3;              // 0..31
  const int ip  = (x >> 2) * 2 + (r & 1);        // i-panel 0..3
  const int jt  = ((x >> 1) & 1) * 2 + ((r >> 1) & 1);  // j-panel 0..3
  const int hg  = (x & 1) * 8 + (r >> 2);        // 0..15
  const int i0  = ip * 128;
  const int j0  = jt * 128;
  const int hg4 = hg * 4;

  const int t = threadIdx.x, lane = t & 63, w = t >> 6;
  const int hl = w & 3, half = w >> 2;
  const int frl = lane & 15, frg = lane >> 4;

  const uint8_t* Apk = ws;
  const uint8_t* Bpk = ws + WS_B_OFF;

  fragc acc[4][8];
#pragma unroll
  for (int m = 0; m < 4; ++m)
#pragma unroll
    for (int n = 0; n < 8; ++n)
      acc[m][n] = (fragc)0.0f;

  // staging: wave (hl, half) loads its h's ko-planes {2*half, 2*half+1}, A and B
  // ws[kq][h][r]: byte = ((kq*64 + h)*512 + row)*16
#define ISSUE(kt, b)                                                               \
  {                                                                                \
    _Pragma("unroll") for (int k2 = 0; k2 < 2; ++k2) {                             \
      const int ko = half * 2 + k2;                                                \
      const size_t kqh = (size_t)(((kt) * 4 + ko) * 64 + hg4 + hl) * 512;          \
      _Pragma("unroll") for (int p = 0; p < 2; ++p) {                              \
        gload16(Apk + (kqh + i0 + p * 64 + lane) * 16,                             \
                lds + (b) * 65536 + hl * 8192 + ko * 2048 + p * 1024);             \
        gload16(Bpk + (kqh + j0 + p * 64 + lane) * 16,                             \
                lds + (b) * 65536 + 32768 + hl * 8192 + ko * 2048 + p * 1024);     \
      }                                                                            \
    }                                                                              \
  }

  ISSUE(0, 0)

  for (int kt = 0; kt < 32; ++kt) {
    __syncthreads();  // drains gloads of tile kt; joins readers of buf b^1
    const int b = kt & 1;
    if (kt < 31) ISSUE(kt + 1, b ^ 1)
    const uint8_t* La = lds + b * 65536 + hl * 8192;
    const uint8_t* Lb = La + 32768;
    bf16x8 fb[8];
#pragma unroll
    for (int n = 0; n < 8; ++n)
      fb[n] = *(const bf16x8*)(Lb + frg * 2048 + (n * 16 + frl) * 16);
#pragma unroll
    for (int m = 0; m < 4; ++m) {
      bf16x8 fa = *(const bf16x8*)(La + frg * 2048 + (half * 64 + m * 16 + frl) * 16);
#pragma unroll
      for (int n = 0; n < 8; ++n)
        acc[m][n] = __builtin_amdgcn_mfma_f32_16x16x32_bf16(fa, fb[n], acc[m][n], 0, 0, 0);
    }
  }
#undef ISSUE

  // epilogue: bounce C through LDS -> 16B/lane NT stores (C never re-read; keep L3 for panels)
  // chunk = 32 i-rows: LDS image [32 i][128 j][4 h] f32 = 64KB, addr-XOR swizzled.
  const float scale = 1.0f / 1024.0f;
  const int i_r = t >> 4, jo = t & 15;
#pragma unroll
  for (int cb = 0; cb < 4; ++cb) {
    __syncthreads();  // chunk cb-1 readers done / K-loop readers done
    if (half == (cb >> 1)) {
#pragma unroll
      for (int m2 = 0; m2 < 2; ++m2) {
        const int m = (cb & 1) * 2 + m2;
#pragma unroll
        for (int n = 0; n < 8; ++n) {
#pragma unroll
          for (int q = 0; q < 4; ++q) {
            const int il = m2 * 16 + frg * 4 + q;   // 0..31
            const int j  = n * 16 + frl;
            int byte = (il * 128 + j) * 16 + hl * 4;
            byte ^= ((byte >> 7) & 7) << 4;
            *(float*)(lds + byte) = acc[m][n][q] * scale;
          }
        }
      }
    }
    __syncthreads();  // chunk image ready
#pragma unroll
    for (int c = 0; c < 8; ++c) {
      int byte = (i_r * 128 + jo * 8 + c) * 16;
      byte ^= ((byte >> 7) & 7) << 4;
      const f32x4 v = *(const f32x4*)(lds + byte);
      __builtin_nontemporal_store(
          v, (f32x4*)(Og + ((size_t)(i0 + cb * 32 + i_r) * 512 + (j0 + jo * 8 + c)) * 64 + hg4));
    }
  }
}

extern "C" void kernel_launch(void* const* d_in, const int* in_sizes, int n_in,
                              void* d_out, int out_size, void* d_ws, size_t ws_size,
                              hipStream_t stream) {
  const float* a = (const float*)d_in[0];
  const float* b = (const float*)d_in[1];
  float* out = (float*)d_out;
  uint8_t* ws = (uint8_t*)d_ws;
  pack_kernel<<<2048, 512, 0, stream>>>(a, b, ws);
  gemm_kernel<<<256, 512, 0, stream>>>(ws, out);
}

// Round 8
// 129.548 us; speedup vs baseline: 2.1187x; 2.1187x over previous
//
#include <hip/hip_runtime.h>
#include <stdint.h>

typedef float f32x4 __attribute__((ext_vector_type(4)));
typedef short bf16x8 __attribute__((ext_vector_type(8)));
typedef float fragc __attribute__((ext_vector_type(4)));
typedef uint32_t u32x4 __attribute__((ext_vector_type(4)));

__device__ __forceinline__ uint32_t pk2(float lo, float hi) {
  // (bf16(lo) | bf16(hi)<<16) via one v_perm_b32 (truncating)
  return __builtin_amdgcn_perm(__float_as_uint(hi), __float_as_uint(lo), 0x07060302u);
}

__device__ __forceinline__ void gload16(const void* g, void* l) {
  __builtin_amdgcn_global_load_lds((const __attribute__((address_space(1))) uint32_t*)g,
                                   (__attribute__((address_space(3))) uint32_t*)l, 16, 0, 0);
}

#define WS_B_OFF 67108864ull  // B'' at ws + 64 MiB

// ---------- Pass 1: [1024 s][512 r][64 h] f32 -> bf16 ws[kq 128][h 64][r 512][16B octet]
// NT loads: originals are touched once -> don't evict packed data from L3.
__global__ __launch_bounds__(512) void pack_kernel(const float* __restrict__ Ag,
                                                   const float* __restrict__ Bg,
                                                   uint8_t* __restrict__ ws) {
  __shared__ alignas(16) uint8_t lds[65536];

  const int bid  = blockIdx.x;
  const int rw   = bid & 7;
  const int kq   = (bid >> 3) & 127;
  const int side = bid >> 10;
  const int t    = threadIdx.x;

  const f32x4* S4 = (const f32x4*)(side ? Bg : Ag);
  uint8_t* dst = ws + (side ? WS_B_OFF : 0ull);

  // window = rows rw*64..+63 (1024 float4); thread owns rows {t>>4, t>>4+32}, h-quad t&15
  const int base = rw * 1024 + t;
  f32x4 r1[8], r2[8];
#pragma unroll
  for (int e = 0; e < 8; ++e) {
    r1[e] = __builtin_nontemporal_load(&S4[(size_t)(kq * 8 + e) * 8192 + base]);
    r2[e] = __builtin_nontemporal_load(&S4[(size_t)(kq * 8 + e) * 8192 + base + 512]);
  }

  const int hq = t & 15;
  const int ra = t >> 4;  // 0..31
#pragma unroll
  for (int e = 0; e < 4; ++e) {
    const int h = hq * 4 + e;
    u32x4 o1, o2;
    o1[0] = pk2(r1[0][e], r1[1][e]); o1[1] = pk2(r1[2][e], r1[3][e]);
    o1[2] = pk2(r1[4][e], r1[5][e]); o1[3] = pk2(r1[6][e], r1[7][e]);
    o2[0] = pk2(r2[0][e], r2[1][e]); o2[1] = pk2(r2[2][e], r2[3][e]);
    o2[2] = pk2(r2[4][e], r2[5][e]); o2[3] = pk2(r2[6][e], r2[7][e]);
    const int s1 = (ra + hq) & 63;
    const int s2 = (ra + 32 + hq) & 63;
    *(u32x4*)(lds + h * 1024 + s1 * 16) = o1;
    *(u32x4*)(lds + h * 1024 + s2 * 16) = o2;
  }
  __syncthreads();

  const int l = t & 63, w = t >> 6;
#pragma unroll
  for (int e2 = 0; e2 < 8; ++e2) {
    const int h  = e2 * 8 + w;
    const int sl = (l + (h >> 2)) & 63;
    const u32x4 v = *(const u32x4*)(lds + h * 1024 + sl * 16);
    *(u32x4*)(dst + ((size_t)(kq * 64 + h) * 512 + rw * 64 + l) * 16) = v;  // cached: feeds gemm
  }
}

// ---------- Pass 2: C[i,j,h] = (1/1024) sum_s A''[.,h,i]*B''[.,h,j]
// tile 128i x 128j x 4h, 512 thr (8 waves: hl = w&3, half = w>>2), BK=32, dbuf LDS 128KB.
// XCD map: x = (i-pair, j-pair, h-half) -> each A/B byte re-read only within its XCD (2x,
// kt-synced -> L2 serves), and all 4 hg-siblings of every C-line are co-XCD (write merge).
__global__ __launch_bounds__(512, 2) void gemm_kernel(const uint8_t* __restrict__ ws,
                                                      float* __restrict__ Og) {
  __shared__ alignas(16) uint8_t lds[131072];  // 2 x (A 32KB + B 32KB)

  const int bid = blockIdx.x;
  const int x   = bid & 7;
  const int r   = bid >> 3;              // 0..31
  const int ip  = (x >> 2) * 2 + (r & 1);        // i-panel 0..3
  const int jt  = ((x >> 1) & 1) * 2 + ((r >> 1) & 1);  // j-panel 0..3
  const int hg  = (x & 1) * 8 + (r >> 2);        // 0..15
  const int i0  = ip * 128;
  const int j0  = jt * 128;
  const int hg4 = hg * 4;

  const int t = threadIdx.x, lane = t & 63, w = t >> 6;
  const int hl = w & 3, half = w >> 2;
  const int frl = lane & 15, frg = lane >> 4;

  const uint8_t* Apk = ws;
  const uint8_t* Bpk = ws + WS_B_OFF;

  fragc acc[4][8];
#pragma unroll
  for (int m = 0; m < 4; ++m)
#pragma unroll
    for (int n = 0; n < 8; ++n)
      acc[m][n] = (fragc)0.0f;

  // staging: wave (hl, half) loads its h's ko-planes {2*half, 2*half+1}, A and B
  // ws[kq][h][r]: byte = ((kq*64 + h)*512 + row)*16
#define ISSUE(kt, b)                                                               \
  {                                                                                \
    _Pragma("unroll") for (int k2 = 0; k2 < 2; ++k2) {                             \
      const int ko = half * 2 + k2;                                                \
      const size_t kqh = (size_t)(((kt) * 4 + ko) * 64 + hg4 + hl) * 512;          \
      _Pragma("unroll") for (int p = 0; p < 2; ++p) {                              \
        gload16(Apk + (kqh + i0 + p * 64 + lane) * 16,                             \
                lds + (b) * 65536 + hl * 8192 + ko * 2048 + p * 1024);             \
        gload16(Bpk + (kqh + j0 + p * 64 + lane) * 16,                             \
                lds + (b) * 65536 + 32768 + hl * 8192 + ko * 2048 + p * 1024);     \
      }                                                                            \
    }                                                                              \
  }

  ISSUE(0, 0)

  for (int kt = 0; kt < 32; ++kt) {
    __syncthreads();  // drains gloads of tile kt; joins readers of buf b^1
    const int b = kt & 1;
    if (kt < 31) ISSUE(kt + 1, b ^ 1)
    const uint8_t* La = lds + b * 65536 + hl * 8192;
    const uint8_t* Lb = La + 32768;
    bf16x8 fb[8];
#pragma unroll
    for (int n = 0; n < 8; ++n)
      fb[n] = *(const bf16x8*)(Lb + frg * 2048 + (n * 16 + frl) * 16);
#pragma unroll
    for (int m = 0; m < 4; ++m) {
      bf16x8 fa = *(const bf16x8*)(La + frg * 2048 + (half * 64 + m * 16 + frl) * 16);
#pragma unroll
      for (int n = 0; n < 8; ++n)
        acc[m][n] = __builtin_amdgcn_mfma_f32_16x16x32_bf16(fa, fb[n], acc[m][n], 0, 0, 0);
    }
  }
#undef ISSUE

  // epilogue: bounce C through LDS -> 16B/lane CACHED stores (L2 merges the 4 hg-sibling
  // stores of each 64B line; NT stores bypass merge -> 4x write amplification, R7 lesson).
  // chunk = 32 i-rows: LDS image [32 i][128 j][4 h] f32 = 64KB, addr-XOR swizzled.
  const float scale = 1.0f / 1024.0f;
  const int i_r = t >> 4, jo = t & 15;
#pragma unroll
  for (int cb = 0; cb < 4; ++cb) {
    __syncthreads();  // chunk cb-1 readers done / K-loop readers done
    if (half == (cb >> 1)) {
#pragma unroll
      for (int m2 = 0; m2 < 2; ++m2) {
        const int m = (cb & 1) * 2 + m2;
#pragma unroll
        for (int n = 0; n < 8; ++n) {
#pragma unroll
          for (int q = 0; q < 4; ++q) {
            const int il = m2 * 16 + frg * 4 + q;   // 0..31
            const int j  = n * 16 + frl;
            int byte = (il * 128 + j) * 16 + hl * 4;
            byte ^= ((byte >> 7) & 7) << 4;
            *(float*)(lds + byte) = acc[m][n][q] * scale;
          }
        }
      }
    }
    __syncthreads();  // chunk image ready
#pragma unroll
    for (int c = 0; c < 8; ++c) {
      int byte = (i_r * 128 + jo * 8 + c) * 16;
      byte ^= ((byte >> 7) & 7) << 4;
      const f32x4 v = *(const f32x4*)(lds + byte);
      *(f32x4*)(Og + ((size_t)(i0 + cb * 32 + i_r) * 512 + (j0 + jo * 8 + c)) * 64 + hg4) = v;
    }
  }
}

extern "C" void kernel_launch(void* const* d_in, const int* in_sizes, int n_in,
                              void* d_out, int out_size, void* d_ws, size_t ws_size,
                              hipStream_t stream) {
  const float* a = (const float*)d_in[0];
  const float* b = (const float*)d_in[1];
  float* out = (float*)d_out;
  uint8_t* ws = (uint8_t*)d_ws;
  pack_kernel<<<2048, 512, 0, stream>>>(a, b, ws);
  gemm_kernel<<<256, 512, 0, stream>>>(ws, out);
}